// Round 2
// baseline (332.948 us; speedup 1.0000x reference)
//
#include <hip/hip_runtime.h>

#define NIB_SCALE 100.0f

// ---- DPP helpers (16-lane "row" ops on the VALU pipe; rows == our groups) ----
// ctrl: 0x101+N row_shl, 0x110+N row_shr, 0x120+N row_ror, 0x140 row_mirror
template<int CTRL>
__device__ __forceinline__ float fdpp(float x) {
    return __int_as_float(__builtin_amdgcn_update_dpp(
        0, __float_as_int(x), CTRL, 0xF, 0xF, true));
}

// full reduction via circular windows (ror 1,2,4,8): every lane gets the total
__device__ __forceinline__ float rsum16d(float v) {
    v += fdpp<0x121>(v);
    v += fdpp<0x122>(v);
    v += fdpp<0x124>(v);
    v += fdpp<0x128>(v);
    return v;
}
__device__ __forceinline__ float rmax16d(float v) {
    v = fmaxf(v, fdpp<0x121>(v));
    v = fmaxf(v, fdpp<0x122>(v));
    v = fmaxf(v, fdpp<0x124>(v));
    v = fmaxf(v, fdpp<0x128>(v));
    return v;
}
// inclusive ascending prefix sum within the 16-lane row (row_shr, 0-filled)
__device__ __forceinline__ float scan16d(float v) {
    v += fdpp<0x111>(v);
    v += fdpp<0x112>(v);
    v += fdpp<0x114>(v);
    v += fdpp<0x118>(v);
    return v;
}

// sharp softmax over 16 values distributed one-per-lane (pure DPP + VALU)
__device__ __forceinline__ float softmax16d(float v) {
    float m = rmax16d(v);
    float e = expf(NIB_SCALE * (v - m));   // accurate exp: absmax margin
    float s = rsum16d(e);
    return e / s;
}

// build G[j][k] = src[(k-j)&15] via independent row_ror:j DPP movs (0 ds ops)
#define GATHER_ROT(dst, src)            \
    dst[0]  = (src);                    \
    dst[1]  = fdpp<0x121>(src);         \
    dst[2]  = fdpp<0x122>(src);         \
    dst[3]  = fdpp<0x123>(src);         \
    dst[4]  = fdpp<0x124>(src);         \
    dst[5]  = fdpp<0x125>(src);         \
    dst[6]  = fdpp<0x126>(src);         \
    dst[7]  = fdpp<0x127>(src);         \
    dst[8]  = fdpp<0x128>(src);         \
    dst[9]  = fdpp<0x129>(src);         \
    dst[10] = fdpp<0x12A>(src);         \
    dst[11] = fdpp<0x12B>(src);         \
    dst[12] = fdpp<0x12C>(src);         \
    dst[13] = fdpp<0x12D>(src);         \
    dst[14] = fdpp<0x12E>(src);         \
    dst[15] = fdpp<0x12F>(src);

__global__ __launch_bounds__(256) void nalu_kernel(const float* __restrict__ A,
                                                   const float* __restrict__ B,
                                                   float* __restrict__ O,
                                                   int nrows) {
    // per-group scratch; groups (16 lanes) never span waves -> wave-synchronous,
    // no __syncthreads needed. Broadcast reads: all 16 lanes same addr.
    __shared__ __align__(16) float sQL[16][16];
    __shared__ __align__(16) float sQH[16][16];
    __shared__ __align__(16) float sPSL[16][16];

    const int tid = threadIdx.x;
    const int k = tid & 15;                       // lane within 16-lane group
    const int g = tid >> 4;                       // group within block
    const int row = blockIdx.x * 16 + g;
    if (row >= nrows) return;
    const long base = (long)row * 1024;

    // incoming carry distribution (softmax2 of [1,0]*100 -> pc1 = 3.7e-44 ~ 0)
    float pc0 = 1.0f, pc1 = 0.0f;

    #pragma unroll
    for (int byte = 0; byte < 4; ++byte) {
        const float* pa = A + base + byte * 256;
        const float* pb = B + base + byte * 256;

        // strided loads: lane k holds column k -> low-nibble sums lane-local
        float sa[16], sb[16];
        #pragma unroll
        for (int e = 0; e < 16; ++e) sa[e] = pa[16 * e + k];
        #pragma unroll
        for (int e = 0; e < 16; ++e) sb[e] = pb[16 * e + k];
        // rowwise float4 loads: lane k holds row k -> high-nibble sums lane-local
        // (same cache lines as strided loads -> L1 hits, no extra HBM traffic)
        const float4* pa4 = (const float4*)(pa + 16 * k);
        const float4* pb4 = (const float4*)(pb + 16 * k);
        float4 ra0 = pa4[0], ra1 = pa4[1], ra2 = pa4[2], ra3 = pa4[3];
        float4 rb0 = pb4[0], rb1 = pb4[1], rb2 = pb4[2], rb3 = pb4[3];

        float al = 0.f, bl = 0.f;
        #pragma unroll
        for (int e = 0; e < 16; ++e) al += sa[e];
        #pragma unroll
        for (int e = 0; e < 16; ++e) bl += sb[e];
        float4 rat = make_float4(ra0.x + ra1.x + ra2.x + ra3.x,
                                 ra0.y + ra1.y + ra2.y + ra3.y,
                                 ra0.z + ra1.z + ra2.z + ra3.z,
                                 ra0.w + ra1.w + ra2.w + ra3.w);
        float4 rbt = make_float4(rb0.x + rb1.x + rb2.x + rb3.x,
                                 rb0.y + rb1.y + rb2.y + rb3.y,
                                 rb0.z + rb1.z + rb2.z + rb3.z,
                                 rb0.w + rb1.w + rb2.w + rb3.w);
        float ah = (rat.x + rat.y) + (rat.z + rat.w);
        float bh = (rbt.x + rbt.y) + (rbt.z + rbt.w);

        // factorized sharp softmaxes (exact vs the joint 512-softmax)
        float pal = softmax16d(al);
        float pbl = softmax16d(bl);
        float pah = softmax16d(ah);
        float pbh = softmax16d(bh);

        // stage q-distributions for uniform-array gather (1 write + 4 bcast reads)
        sQL[g][k] = pbl;
        sQH[g][k] = pbh;

        // overflow masses, pure DPP:
        // mir[k] = q[15-k]; T15[k] = sum_{b>=15-k} q[b] = incl-scan(mir)
        float mirl = fdpp<0x140>(pbl);
        float mirh = fdpp<0x140>(pbh);
        float T15l = scan16d(mirl);
        float T15h = scan16d(mirh);
        float ov15l = rsum16d(pal * T15l);   // sum_{a+b>=15} p[a] q[b]
        float c15l  = rsum16d(pal * mirl);   // sum_{a+b==15}
        float ov15h = rsum16d(pah * T15h);
        float c15h  = rsum16d(pah * mirh);
        float ov16l = ov15l - c15l;
        float ov16h = ov15h - c15h;

        // gather q arrays (identical content in all 16 lanes of the group)
        float QL[16], QH[16];
        *(float4*)&QL[0]  = *(const float4*)&sQL[g][0];
        *(float4*)&QL[4]  = *(const float4*)&sQL[g][4];
        *(float4*)&QL[8]  = *(const float4*)&sQL[g][8];
        *(float4*)&QL[12] = *(const float4*)&sQL[g][12];
        *(float4*)&QH[0]  = *(const float4*)&sQH[g][0];
        *(float4*)&QH[4]  = *(const float4*)&sQH[g][4];
        *(float4*)&QH[8]  = *(const float4*)&sQH[g][8];
        *(float4*)&QH[12] = *(const float4*)&sQH[g][12];

        // circular convolution r[k] = sum_j p[(k-j)&15] * q[j]  (lane-local FMAs)
        float GL[16], GH[16];
        GATHER_ROT(GL, pal)
        GATHER_ROT(GH, pah)
        float rl = 0.f, rh = 0.f;
        #pragma unroll
        for (int j = 0; j < 16; ++j) {
            rl = fmaf(GL[j], QL[j], rl);
            rh = fmaf(GH[j], QH[j], rh);
        }

        // low nibble add with incoming carry
        float rlm1  = fdpp<0x121>(rl);            // rl[(k-1)&15]
        float slow  = pc0 * rl + pc1 * rlm1;
        float coutl = pc0 * ov16l + pc1 * ov15l;
        // carry sharpen: softmax2(100*[1-c, c]) = sigmoid(100*(2c-1))
        float qc1 = 1.0f / (1.0f + expf(NIB_SCALE * (1.0f - 2.0f * coutl)));
        float qc0 = 1.0f - qc1;

        // high nibble add
        float rhm1  = fdpp<0x121>(rh);
        float shigh = qc0 * rh + qc1 * rhm1;
        float couth = qc0 * ov16h + qc1 * ov15h;
        pc1 = 1.0f / (1.0f + expf(NIB_SCALE * (1.0f - 2.0f * couth)));
        pc0 = 1.0f - pc1;

        // n2b: o[16h + l] = psh[h]*psl[l]; lane k owns h == k (psh lane-local!)
        float psl = softmax16d(slow);
        float psh = softmax16d(shigh);

        sPSL[g][k] = psl;
        float PSL[16];
        *(float4*)&PSL[0]  = *(const float4*)&sPSL[g][0];
        *(float4*)&PSL[4]  = *(const float4*)&sPSL[g][4];
        *(float4*)&PSL[8]  = *(const float4*)&sPSL[g][8];
        *(float4*)&PSL[12] = *(const float4*)&sPSL[g][12];

        float* po = O + base + byte * 256 + 16 * k;
        #pragma unroll
        for (int c = 0; c < 4; ++c) {
            float4 o4 = make_float4(psh * PSL[4 * c + 0], psh * PSL[4 * c + 1],
                                    psh * PSL[4 * c + 2], psh * PSL[4 * c + 3]);
            *(float4*)(po + 4 * c) = o4;
        }
    }
}

extern "C" void kernel_launch(void* const* d_in, const int* in_sizes, int n_in,
                              void* d_out, int out_size, void* d_ws, size_t ws_size,
                              hipStream_t stream) {
    const float* A = (const float*)d_in[0];
    const float* B = (const float*)d_in[1];
    float* O = (float*)d_out;
    int nrows = in_sizes[0] / 1024;          // [B,4,256] -> B
    int grid = (nrows + 15) / 16;            // 16 rows per 256-thread block
    nalu_kernel<<<grid, 256, 0, stream>>>(A, B, O, nrows);
}

// Round 3
// 303.763 us; speedup vs baseline: 1.0961x; 1.0961x over previous
//
#include <hip/hip_runtime.h>

#define NIB_SCALE 100.0f

// ---- DPP helpers (16-lane "row" ops on the VALU pipe; rows == nibble groups) ----
// ctrl: 0x110+N row_shr, 0x120+N row_ror, 0x140 row_mirror
template<int CTRL>
__device__ __forceinline__ float fdpp(float x) {
    return __int_as_float(__builtin_amdgcn_update_dpp(
        0, __float_as_int(x), CTRL, 0xF, 0xF, true));
}

__device__ __forceinline__ float rsum16d(float v) {
    v += fdpp<0x121>(v); v += fdpp<0x122>(v); v += fdpp<0x124>(v); v += fdpp<0x128>(v);
    return v;
}
__device__ __forceinline__ float rmax16d(float v) {
    v = fmaxf(v, fdpp<0x121>(v)); v = fmaxf(v, fdpp<0x122>(v));
    v = fmaxf(v, fdpp<0x124>(v)); v = fmaxf(v, fdpp<0x128>(v));
    return v;
}
// inclusive ascending prefix sum within the 16-lane row
__device__ __forceinline__ float scan16d(float v) {
    v += fdpp<0x111>(v); v += fdpp<0x112>(v); v += fdpp<0x114>(v); v += fdpp<0x118>(v);
    return v;
}
__device__ __forceinline__ float softmax16d(float v) {
    float m = rmax16d(v);
    float e = __expf(NIB_SCALE * (v - m));
    float s = rsum16d(e);
    return e / s;
}
__device__ __forceinline__ float sharp_sigmoid(float c) {
    // softmax2(100*[1-c, c])[1] = 1/(1+exp(100*(1-2c)))
    return 1.0f / (1.0f + __expf(NIB_SCALE * (1.0f - 2.0f * c)));
}

// build G[j][k] = src[(k-j)&15] via independent row_ror:j DPP movs
#define GATHER_ROT(dst, src)            \
    dst[0]  = (src);                    \
    dst[1]  = fdpp<0x121>(src);         \
    dst[2]  = fdpp<0x122>(src);         \
    dst[3]  = fdpp<0x123>(src);         \
    dst[4]  = fdpp<0x124>(src);         \
    dst[5]  = fdpp<0x125>(src);         \
    dst[6]  = fdpp<0x126>(src);         \
    dst[7]  = fdpp<0x127>(src);         \
    dst[8]  = fdpp<0x128>(src);         \
    dst[9]  = fdpp<0x129>(src);         \
    dst[10] = fdpp<0x12A>(src);         \
    dst[11] = fdpp<0x12B>(src);         \
    dst[12] = fdpp<0x12C>(src);         \
    dst[13] = fdpp<0x12D>(src);         \
    dst[14] = fdpp<0x12E>(src);         \
    dst[15] = fdpp<0x12F>(src);

// One wave = one 4-byte row. The wave's four 16-lane DPP rows handle the four
// bytes IN PARALLEL (all heavy work is carry-independent); only the tiny
// carry chain is serial, computed redundantly from LDS-broadcast scalars.
__global__ __launch_bounds__(256) void nalu_kernel(const float* __restrict__ A,
                                                   const float* __restrict__ B,
                                                   float* __restrict__ O,
                                                   int nrows) {
    // all cross-lane LDS traffic stays inside one wave -> no barriers needed
    __shared__ __align__(16) float sQL[16][16];
    __shared__ __align__(16) float sQH[16][16];
    __shared__ __align__(16) float sPSL[16][16];
    __shared__ __align__(16) float sPSH[16][16];
    __shared__ __align__(16) float sOV[4][4][4];  // [wave][{o16l,o15l,o16h,o15h}][byte]

    const int tid = threadIdx.x;
    const int k = tid & 15;           // nibble-value lane within the 16-lane group
    const int g = tid >> 4;           // group id within block (16 groups)
    const int b = g & 3;              // byte index handled by this group
    const int w = tid >> 6;           // wave id within block == row within block
    const int row = blockIdx.x * 4 + w;
    if (row >= nrows) return;
    const long base = (long)row * 1024 + b * 256;

    const float* pa = A + base;
    const float* pb = B + base;

    // ---- b2n ----
    // low-nibble logits = column sums of the 16x16 block: strided dword loads
    float a0 = 0, a1 = 0, a2 = 0, a3 = 0, b0 = 0, b1 = 0, b2 = 0, b3 = 0;
    #pragma unroll
    for (int e = 0; e < 4; ++e) {
        a0 += pa[16 * e + k];        b0 += pb[16 * e + k];
        a1 += pa[16 * (e + 4) + k];  b1 += pb[16 * (e + 4) + k];
        a2 += pa[16 * (e + 8) + k];  b2 += pb[16 * (e + 8) + k];
        a3 += pa[16 * (e + 12) + k]; b3 += pb[16 * (e + 12) + k];
    }
    float al = (a0 + a1) + (a2 + a3);
    float bl = (b0 + b1) + (b2 + b3);
    // high-nibble logits = row sums: float4 loads (same lines -> L1 hits)
    const float4* pa4 = (const float4*)(pa + 16 * k);
    const float4* pb4 = (const float4*)(pb + 16 * k);
    float4 ra0 = pa4[0], ra1 = pa4[1], ra2 = pa4[2], ra3 = pa4[3];
    float4 rb0 = pb4[0], rb1 = pb4[1], rb2 = pb4[2], rb3 = pb4[3];
    float ah = ((ra0.x + ra0.y) + (ra0.z + ra0.w)) + ((ra1.x + ra1.y) + (ra1.z + ra1.w))
             + ((ra2.x + ra2.y) + (ra2.z + ra2.w)) + ((ra3.x + ra3.y) + (ra3.z + ra3.w));
    float bh = ((rb0.x + rb0.y) + (rb0.z + rb0.w)) + ((rb1.x + rb1.y) + (rb1.z + rb1.w))
             + ((rb2.x + rb2.y) + (rb2.z + rb2.w)) + ((rb3.x + rb3.y) + (rb3.z + rb3.w));

    // factorized sharp softmaxes (exact vs the joint 512-softmax)
    float pal = softmax16d(al);
    float pbl = softmax16d(bl);
    float pah = softmax16d(ah);
    float pbh = softmax16d(bh);

    sQL[g][k] = pbl;
    sQH[g][k] = pbh;

    // overflow masses, pure DPP:
    // mir[k]=q[15-k]; T15[k]=sum_{v>=15-k} q[v]; ov15=sum_{a+v>=15} p[a]q[v]
    float mirl = fdpp<0x140>(pbl);
    float mirh = fdpp<0x140>(pbh);
    float T15l = scan16d(mirl);
    float T15h = scan16d(mirh);
    float ov15l = rsum16d(pal * T15l);
    float c15l  = rsum16d(pal * mirl);
    float ov15h = rsum16d(pah * T15h);
    float c15h  = rsum16d(pah * mirh);
    float ov16l = ov15l - c15l;
    float ov16h = ov15h - c15h;

    // publish per-byte carry constants (uniform within group; benign dup writes)
    sOV[w][0][b] = ov16l;
    sOV[w][1][b] = ov15l;
    sOV[w][2][b] = ov16h;
    sOV[w][3][b] = ov15h;

    // ---- circular convolutions r[k] = sum_j p[(k-j)&15] q[j] ----
    float QL[16], QH[16];
    *(float4*)&QL[0]  = *(const float4*)&sQL[g][0];
    *(float4*)&QL[4]  = *(const float4*)&sQL[g][4];
    *(float4*)&QL[8]  = *(const float4*)&sQL[g][8];
    *(float4*)&QL[12] = *(const float4*)&sQL[g][12];
    float GL[16];
    GATHER_ROT(GL, pal)
    float rl = 0.f;
    #pragma unroll
    for (int j = 0; j < 16; ++j) rl = fmaf(GL[j], QL[j], rl);

    *(float4*)&QH[0]  = *(const float4*)&sQH[g][0];
    *(float4*)&QH[4]  = *(const float4*)&sQH[g][4];
    *(float4*)&QH[8]  = *(const float4*)&sQH[g][8];
    *(float4*)&QH[12] = *(const float4*)&sQH[g][12];
    float GH[16];
    GATHER_ROT(GH, pah)
    float rh = 0.f;
    #pragma unroll
    for (int j = 0; j < 16; ++j) rh = fmaf(GH[j], QH[j], rh);

    // ---- serial carry chain (tiny; redundantly computed by every lane) ----
    float4 O16L = *(const float4*)&sOV[w][0][0];
    float4 O15L = *(const float4*)&sOV[w][1][0];
    float4 O16H = *(const float4*)&sOV[w][2][0];
    float4 O15H = *(const float4*)&sOV[w][3][0];

    // byte 0: incoming pc = (1, 0)  (softmax2([1,0]*100): pc1 = 3.7e-44 ~ 0)
    float qc1_0 = sharp_sigmoid(O16L.x);
    float qc0_0 = 1.f - qc1_0;
    float pc1_1 = sharp_sigmoid(qc0_0 * O16H.x + qc1_0 * O15H.x);
    float pc0_1 = 1.f - pc1_1;
    // byte 1
    float qc1_1 = sharp_sigmoid(pc0_1 * O16L.y + pc1_1 * O15L.y);
    float qc0_1 = 1.f - qc1_1;
    float pc1_2 = sharp_sigmoid(qc0_1 * O16H.y + qc1_1 * O15H.y);
    float pc0_2 = 1.f - pc1_2;
    // byte 2
    float qc1_2 = sharp_sigmoid(pc0_2 * O16L.z + pc1_2 * O15L.z);
    float qc0_2 = 1.f - qc1_2;
    float pc1_3 = sharp_sigmoid(qc0_2 * O16H.z + qc1_2 * O15H.z);
    float pc0_3 = 1.f - pc1_3;
    // byte 3
    float qc1_3 = sharp_sigmoid(pc0_3 * O16L.w + pc1_3 * O15L.w);
    float qc0_3 = 1.f - qc1_3;

    // select this group's byte position (b is group-uniform -> cheap cndmasks)
    float pc0 = b == 0 ? 1.f   : b == 1 ? pc0_1 : b == 2 ? pc0_2 : pc0_3;
    float pc1 = b == 0 ? 0.f   : b == 1 ? pc1_1 : b == 2 ? pc1_2 : pc1_3;
    float qc0 = b == 0 ? qc0_0 : b == 1 ? qc0_1 : b == 2 ? qc0_2 : qc0_3;
    float qc1 = b == 0 ? qc1_0 : b == 1 ? qc1_1 : b == 2 ? qc1_2 : qc1_3;

    // ---- nibble sums with carry mixing ----
    float slow  = pc0 * rl + pc1 * fdpp<0x121>(rl);   // rl[(k-1)&15]
    float shigh = qc0 * rh + qc1 * fdpp<0x121>(rh);

    // ---- n2b: out[16h + l] = psh[h] * psl[l] ----
    float psl = softmax16d(slow);
    float psh = softmax16d(shigh);
    sPSL[g][k] = psl;
    sPSH[g][k] = psh;

    // full-cache-line stores: instr c writes group's bytes [64c .. 64c+63]
    float4 pslq = *(const float4*)&sPSL[g][4 * (k & 3)];
    float* po = O + base;
    #pragma unroll
    for (int c = 0; c < 4; ++c) {
        float hs = sPSH[g][4 * c + (k >> 2)];
        float4 o4 = make_float4(hs * pslq.x, hs * pslq.y, hs * pslq.z, hs * pslq.w);
        *(float4*)(po + 64 * c + 4 * k) = o4;
    }
}

extern "C" void kernel_launch(void* const* d_in, const int* in_sizes, int n_in,
                              void* d_out, int out_size, void* d_ws, size_t ws_size,
                              hipStream_t stream) {
    const float* A = (const float*)d_in[0];
    const float* B = (const float*)d_in[1];
    float* O = (float*)d_out;
    int nrows = in_sizes[0] / 1024;          // [B,4,256] -> B
    int grid = (nrows + 3) / 4;              // 4 rows (waves) per 256-thread block
    nalu_kernel<<<grid, 256, 0, stream>>>(A, B, O, nrows);
}